// Round 15
// baseline (20.926 us; speedup 1.0000x reference)
//
#include <hip/hip_runtime.h>

// ProSurv similarity loss, collapsed:
//   cm[b,c] = (h[b] . bankbar[c]) / max(||h[b]||, eps)
//   bankbar[c] = (1/M) sum_m bank[c,m] / max(||bank[c,m]||, eps)
// 3 dispatches, no memsets, NO cross-block synchronization of any kind:
//   1) bank_partial_kernel: 128 blocks write 128 partial vectors (plain
//      stores; pure writer — fence/counter finalize was the R10/R11/R13
//      poison and is gone).
//   2) loss_kernel: 512 blocks; staging phase sums the 16 partials/combo
//      in-block (visibility via dispatch boundary — race-free by design),
//      then 8 threads/sample LDS compute (R8 structure, proven fastest).
//   3) final_kernel: 1 block sums lpart -> out[0] (single d_out store).

constexpr int NC = 4;     // classes
constexpr int NM = 512;   // prototypes per class
constexpr int ND = 256;   // feature dim
constexpr float EPSF = 1e-12f;

constexpr int ABLK = 128;                             // bank partial blocks
constexpr int ROWS_PER_ABLK  = 2 * NC * NM / ABLK;    // 32
constexpr int ROWS_PER_AWAVE = ROWS_PER_ABLK / 4;     // 8
constexpr int PART_PER_COMBO = ABLK / (2 * NC);       // 16

constexpr int BBLK = 512;                             // loss blocks
constexpr int SPB  = 32;                              // samples per loss block
constexpr int CHW  = 36;                              // padded chunk width (32+4)
constexpr int SROW = 8 * CHW;                         // 288 floats per padded row

__device__ __forceinline__ float wave_reduce(float v) {
#pragma unroll
    for (int off = 32; off >= 1; off >>= 1)
        v += __shfl_xor(v, off, 64);
    return v;
}

// ---- Kernel 1: normalized-row partial sums (pure writer, no sync) ----
__global__ __launch_bounds__(256) void bank_partial_kernel(
    const float* __restrict__ pbank, const float* __restrict__ gbank,
    float* __restrict__ partials)
{
    const int blk  = blockIdx.x;
    const int wave = threadIdx.x >> 6;
    const int lane = threadIdx.x & 63;

    float4 acc = {0.f, 0.f, 0.f, 0.f};
    const int r0 = blk * ROWS_PER_ABLK + wave * ROWS_PER_AWAVE;
#pragma unroll
    for (int rr = 0; rr < ROWS_PER_AWAVE; ++rr) {
        const int r      = r0 + rr;
        const int bank   = r >> 11;
        const int within = r & (NC * NM - 1);
        const float* src = (bank ? gbank : pbank) + (size_t)within * ND;
        const float4 v = reinterpret_cast<const float4*>(src)[lane];
        float ss = v.x * v.x + v.y * v.y + v.z * v.z + v.w * v.w;
        ss = wave_reduce(ss);
        const float inv = 1.0f / (fmaxf(sqrtf(ss), EPSF) * (float)NM);
        acc.x += v.x * inv; acc.y += v.y * inv;
        acc.z += v.z * inv; acc.w += v.w * inv;
    }

    __shared__ float4 red[4][64];
    red[wave][lane] = acc;
    __syncthreads();
    if (wave == 0) {
        float4 a = red[0][lane], b = red[1][lane];
        float4 c = red[2][lane], d = red[3][lane];
        a.x += b.x + c.x + d.x; a.y += b.y + c.y + d.y;
        a.z += b.z + c.z + d.z; a.w += b.w + c.w + d.w;
        reinterpret_cast<float4*>(partials + (size_t)blk * ND)[lane] = a;
    }
}

// ---- Kernel 2: loss; in-block bankbar reduce + 8 thr/sample compute ----
__global__ __launch_bounds__(256) void loss_kernel(
    const float* __restrict__ hp, const float* __restrict__ hg,
    const int* __restrict__ label, const int* __restrict__ censor,
    const float* __restrict__ partials, float* __restrict__ lpart)
{
    __shared__ __align__(16) float hbuf[SPB * SROW];   // 36 KiB, reused per modality
    __shared__ __align__(16) float bb[8 * SROW];       // 9 KiB padded bankbar

    const int t = threadIdx.x;
    const int s = t >> 3;          // sample slot 0..31
    const int k = t & 7;           // dim-chunk 0..7 (32 dims each)
    const int sg = blockIdx.x * SPB + s;     // global sample

    // build padded bankbar in-block: 512 float4 columns, 2 per thread;
    // each = sum of this combo's 16 partials (128KB broadcast, L2-hot)
    const float4* p4 = reinterpret_cast<const float4*>(partials);
#pragma unroll
    for (int it = 0; it < 2; ++it) {
        const int f4    = t + it * 256;       // 0..511
        const int combo = f4 >> 6;
        const int rem   = f4 & 63;
        float4 sv = {0.f, 0.f, 0.f, 0.f};
#pragma unroll
        for (int p = 0; p < PART_PER_COMBO; ++p) {
            const float4 v = p4[(size_t)(combo * PART_PER_COMBO + p) * 64 + rem];
            sv.x += v.x; sv.y += v.y; sv.z += v.z; sv.w += v.w;
        }
        *reinterpret_cast<float4*>(&bb[combo * SROW + (rem >> 3) * CHW + (rem & 7) * 4]) = sv;
    }

    const int l   = label[sg];
    const bool evt = (censor[sg] == 0);

    float s0[2], sc[2][NC];

#pragma unroll
    for (int md = 0; md < 2; ++md) {
        // stage 32 rows (32 KB) coalesced -> padded LDS
        const float* src = (md ? hg : hp) + (size_t)blockIdx.x * SPB * ND;
        __syncthreads();   // protect hbuf from previous modality's readers
#pragma unroll
        for (int it = 0; it < 8; ++it) {
            const int f4  = t + it * 256;           // 0..2047
            const int ss  = f4 >> 6;                // sample slot
            const int rem = f4 & 63;
            const float4 v = reinterpret_cast<const float4*>(src)[f4];
            *reinterpret_cast<float4*>(&hbuf[ss * SROW + (rem >> 3) * CHW + (rem & 7) * 4]) = v;
        }
        __syncthreads();

        // per-thread: own 32-dim chunk of own sample
        const float* hrow = &hbuf[s * SROW + k * CHW];
        float4 hx[8];
#pragma unroll
        for (int j = 0; j < 8; ++j)
            hx[j] = reinterpret_cast<const float4*>(hrow)[j];

        float a0 = 0.f;
#pragma unroll
        for (int j = 0; j < 8; ++j)
            a0 += hx[j].x * hx[j].x + hx[j].y * hx[j].y
                + hx[j].z * hx[j].z + hx[j].w * hx[j].w;

        float ac[NC];
#pragma unroll
        for (int c = 0; c < NC; ++c) {
            const float* brow = &bb[(md * NC + c) * SROW + k * CHW];
            float acc = 0.f;
#pragma unroll
            for (int j = 0; j < 8; ++j) {
                const float4 w = reinterpret_cast<const float4*>(brow)[j];
                acc += hx[j].x * w.x + hx[j].y * w.y
                     + hx[j].z * w.z + hx[j].w * w.w;
            }
            ac[c] = acc;
        }

        // 3-step butterfly over the 8-lane group (all lanes get totals)
#pragma unroll
        for (int off = 1; off <= 4; off <<= 1) {
            a0 += __shfl_xor(a0, off, 64);
#pragma unroll
            for (int c = 0; c < NC; ++c)
                ac[c] += __shfl_xor(ac[c], off, 64);
        }
        s0[md] = a0;
#pragma unroll
        for (int c = 0; c < NC; ++c) sc[md][c] = ac[c];
    }

    // per-thread loss (group-replicated; only k==0 contributes)
    float contrib = 0.0f;
#pragma unroll
    for (int md = 0; md < 2; ++md) {
        const float inv = 1.0f / fmaxf(sqrtf(s0[md]), EPSF);
        float sum = 0.f, cml = 0.f, sge = 0.f, slt = 0.f;
#pragma unroll
        for (int c = 0; c < NC; ++c) {
            const float x = sc[md][c] * inv;
            sum += x;
            if (c == l) cml = x;
            if (c >= l) sge += x; else slt += x;
        }
        float pos, neg;
        if (evt) {
            pos = cml;
            neg = (sum - cml) * (1.0f / (NC - 1));
        } else {
            pos = sge / (float)(NC - l);          // l==0 -> pos_all
            neg = slt / (float)(l > 0 ? l : 1);   // l==0 -> 0
        }
        contrib += neg - pos;
    }
    if (k != 0) contrib = 0.0f;

    // block reduction -> lpart
    contrib = wave_reduce(contrib);
    __shared__ float wpart[4];
    if ((t & 63) == 0) wpart[t >> 6] = contrib;
    __syncthreads();
    if (t == 0)
        lpart[blockIdx.x] = wpart[0] + wpart[1] + wpart[2] + wpart[3];
}

// ---- Kernel 3: one block sums BBLK partials -> out[0] ----
__global__ __launch_bounds__(256) void final_kernel(
    const float* __restrict__ lpart, float* __restrict__ out)
{
    const int t = threadIdx.x;
    float v = lpart[t] + lpart[t + 256];
    v = wave_reduce(v);
    __shared__ float wp[4];
    if ((t & 63) == 0) wp[t >> 6] = v;
    __syncthreads();
    if (t == 0) out[0] = wp[0] + wp[1] + wp[2] + wp[3];
}

extern "C" void kernel_launch(void* const* d_in, const int* in_sizes, int n_in,
                              void* d_out, int out_size, void* d_ws, size_t ws_size,
                              hipStream_t stream)
{
    const float* hp     = (const float*)d_in[0];
    const float* hg     = (const float*)d_in[1];
    const float* pb     = (const float*)d_in[2];
    const float* gb     = (const float*)d_in[3];
    const int*   label  = (const int*)d_in[4];
    const int*   censor = (const int*)d_in[5];
    float*       out    = (float*)d_out;

    float* partials = (float*)d_ws;                           // ABLK*ND = 128 KiB
    float* lpart    = partials + (size_t)ABLK * ND;           // BBLK floats

    bank_partial_kernel<<<ABLK, 256, 0, stream>>>(pb, gb, partials);
    loss_kernel        <<<BBLK, 256, 0, stream>>>(hp, hg, label, censor,
                                                  partials, lpart);
    final_kernel       <<<1,    256, 0, stream>>>(lpart, out);
}

// Round 16
// 20.238 us; speedup vs baseline: 1.0340x; 1.0340x over previous
//
#include <hip/hip_runtime.h>

// ProSurv similarity loss, collapsed:
//   cm[b,c] = (h[b] . bankbar[c]) / max(||h[b]||, eps)
//   bankbar[c] = (1/M) sum_m bank[c,m] / max(||bank[c,m]||, eps)
// 3 dispatches, no memsets, NO cross-block synchronization of any kind:
//   1) bank_partial_kernel: 64 blocks write 64 partial vectors (plain stores).
//   2) loss_kernel: 512 blocks; staging phase sums the 8 partials/combo
//      in-block (visibility via dispatch boundary — race-free by design;
//      R13 proved last-block fence handoff loses cross-XCD races), then
//      8 threads/sample LDS compute (R8 structure, proven fastest).
//   3) final_kernel: 1 block sums lpart -> out[0] (single d_out store).
// Session-measured optimum (R14 = 19.6 us); every single-variable deviation
// measured worse (R9..R13, R15).

constexpr int NC = 4;     // classes
constexpr int NM = 512;   // prototypes per class
constexpr int ND = 256;   // feature dim
constexpr float EPSF = 1e-12f;

constexpr int ABLK = 64;                              // bank partial blocks
constexpr int ROWS_PER_ABLK  = 2 * NC * NM / ABLK;    // 64
constexpr int ROWS_PER_AWAVE = ROWS_PER_ABLK / 4;     // 16
constexpr int PART_PER_COMBO = ABLK / (2 * NC);       // 8

constexpr int BBLK = 512;                             // loss blocks
constexpr int SPB  = 32;                              // samples per loss block
constexpr int CHW  = 36;                              // padded chunk width (32+4)
constexpr int SROW = 8 * CHW;                         // 288 floats per padded row

__device__ __forceinline__ float wave_reduce(float v) {
#pragma unroll
    for (int off = 32; off >= 1; off >>= 1)
        v += __shfl_xor(v, off, 64);
    return v;
}

// ---- Kernel 1: normalized-row partial sums (pure writer, no sync) ----
__global__ __launch_bounds__(256) void bank_partial_kernel(
    const float* __restrict__ pbank, const float* __restrict__ gbank,
    float* __restrict__ partials)
{
    const int blk  = blockIdx.x;
    const int wave = threadIdx.x >> 6;
    const int lane = threadIdx.x & 63;

    float4 acc = {0.f, 0.f, 0.f, 0.f};
    const int r0 = blk * ROWS_PER_ABLK + wave * ROWS_PER_AWAVE;
#pragma unroll
    for (int rr = 0; rr < ROWS_PER_AWAVE; ++rr) {
        const int r      = r0 + rr;
        const int bank   = r >> 11;
        const int within = r & (NC * NM - 1);
        const float* src = (bank ? gbank : pbank) + (size_t)within * ND;
        const float4 v = reinterpret_cast<const float4*>(src)[lane];
        float ss = v.x * v.x + v.y * v.y + v.z * v.z + v.w * v.w;
        ss = wave_reduce(ss);
        const float inv = 1.0f / (fmaxf(sqrtf(ss), EPSF) * (float)NM);
        acc.x += v.x * inv; acc.y += v.y * inv;
        acc.z += v.z * inv; acc.w += v.w * inv;
    }

    __shared__ float4 red[4][64];
    red[wave][lane] = acc;
    __syncthreads();
    if (wave == 0) {
        float4 a = red[0][lane], b = red[1][lane];
        float4 c = red[2][lane], d = red[3][lane];
        a.x += b.x + c.x + d.x; a.y += b.y + c.y + d.y;
        a.z += b.z + c.z + d.z; a.w += b.w + c.w + d.w;
        reinterpret_cast<float4*>(partials + (size_t)blk * ND)[lane] = a;
    }
}

// ---- Kernel 2: loss; in-block bankbar reduce + 8 thr/sample compute ----
__global__ __launch_bounds__(256) void loss_kernel(
    const float* __restrict__ hp, const float* __restrict__ hg,
    const int* __restrict__ label, const int* __restrict__ censor,
    const float* __restrict__ partials, float* __restrict__ lpart)
{
    __shared__ __align__(16) float hbuf[SPB * SROW];   // 36 KiB, reused per modality
    __shared__ __align__(16) float bb[8 * SROW];       // 9 KiB padded bankbar

    const int t = threadIdx.x;
    const int s = t >> 3;          // sample slot 0..31
    const int k = t & 7;           // dim-chunk 0..7 (32 dims each)
    const int sg = blockIdx.x * SPB + s;     // global sample

    // build padded bankbar in-block: 512 float4 columns, 2 per thread;
    // each = sum of this combo's 8 partials (64KB broadcast, L2/IF$-hot)
    const float4* p4 = reinterpret_cast<const float4*>(partials);
#pragma unroll
    for (int it = 0; it < 2; ++it) {
        const int f4    = t + it * 256;       // 0..511
        const int combo = f4 >> 6;
        const int rem   = f4 & 63;
        float4 sv = {0.f, 0.f, 0.f, 0.f};
#pragma unroll
        for (int p = 0; p < PART_PER_COMBO; ++p) {
            const float4 v = p4[(size_t)(combo * PART_PER_COMBO + p) * 64 + rem];
            sv.x += v.x; sv.y += v.y; sv.z += v.z; sv.w += v.w;
        }
        *reinterpret_cast<float4*>(&bb[combo * SROW + (rem >> 3) * CHW + (rem & 7) * 4]) = sv;
    }

    const int l   = label[sg];
    const bool evt = (censor[sg] == 0);

    float s0[2], sc[2][NC];

#pragma unroll
    for (int md = 0; md < 2; ++md) {
        // stage 32 rows (32 KB) coalesced -> padded LDS
        const float* src = (md ? hg : hp) + (size_t)blockIdx.x * SPB * ND;
        __syncthreads();   // protect hbuf from previous modality's readers
#pragma unroll
        for (int it = 0; it < 8; ++it) {
            const int f4  = t + it * 256;           // 0..2047
            const int ss  = f4 >> 6;                // sample slot
            const int rem = f4 & 63;
            const float4 v = reinterpret_cast<const float4*>(src)[f4];
            *reinterpret_cast<float4*>(&hbuf[ss * SROW + (rem >> 3) * CHW + (rem & 7) * 4]) = v;
        }
        __syncthreads();

        // per-thread: own 32-dim chunk of own sample
        const float* hrow = &hbuf[s * SROW + k * CHW];
        float4 hx[8];
#pragma unroll
        for (int j = 0; j < 8; ++j)
            hx[j] = reinterpret_cast<const float4*>(hrow)[j];

        float a0 = 0.f;
#pragma unroll
        for (int j = 0; j < 8; ++j)
            a0 += hx[j].x * hx[j].x + hx[j].y * hx[j].y
                + hx[j].z * hx[j].z + hx[j].w * hx[j].w;

        float ac[NC];
#pragma unroll
        for (int c = 0; c < NC; ++c) {
            const float* brow = &bb[(md * NC + c) * SROW + k * CHW];
            float acc = 0.f;
#pragma unroll
            for (int j = 0; j < 8; ++j) {
                const float4 w = reinterpret_cast<const float4*>(brow)[j];
                acc += hx[j].x * w.x + hx[j].y * w.y
                     + hx[j].z * w.z + hx[j].w * w.w;
            }
            ac[c] = acc;
        }

        // 3-step butterfly over the 8-lane group (all lanes get totals)
#pragma unroll
        for (int off = 1; off <= 4; off <<= 1) {
            a0 += __shfl_xor(a0, off, 64);
#pragma unroll
            for (int c = 0; c < NC; ++c)
                ac[c] += __shfl_xor(ac[c], off, 64);
        }
        s0[md] = a0;
#pragma unroll
        for (int c = 0; c < NC; ++c) sc[md][c] = ac[c];
    }

    // per-thread loss (group-replicated; only k==0 contributes)
    float contrib = 0.0f;
#pragma unroll
    for (int md = 0; md < 2; ++md) {
        const float inv = 1.0f / fmaxf(sqrtf(s0[md]), EPSF);
        float sum = 0.f, cml = 0.f, sge = 0.f, slt = 0.f;
#pragma unroll
        for (int c = 0; c < NC; ++c) {
            const float x = sc[md][c] * inv;
            sum += x;
            if (c == l) cml = x;
            if (c >= l) sge += x; else slt += x;
        }
        float pos, neg;
        if (evt) {
            pos = cml;
            neg = (sum - cml) * (1.0f / (NC - 1));
        } else {
            pos = sge / (float)(NC - l);          // l==0 -> pos_all
            neg = slt / (float)(l > 0 ? l : 1);   // l==0 -> 0
        }
        contrib += neg - pos;
    }
    if (k != 0) contrib = 0.0f;

    // block reduction -> lpart
    contrib = wave_reduce(contrib);
    __shared__ float wpart[4];
    if ((t & 63) == 0) wpart[t >> 6] = contrib;
    __syncthreads();
    if (t == 0)
        lpart[blockIdx.x] = wpart[0] + wpart[1] + wpart[2] + wpart[3];
}

// ---- Kernel 3: one block sums BBLK partials -> out[0] ----
__global__ __launch_bounds__(256) void final_kernel(
    const float* __restrict__ lpart, float* __restrict__ out)
{
    const int t = threadIdx.x;
    float v = lpart[t] + lpart[t + 256];
    v = wave_reduce(v);
    __shared__ float wp[4];
    if ((t & 63) == 0) wp[t >> 6] = v;
    __syncthreads();
    if (t == 0) out[0] = wp[0] + wp[1] + wp[2] + wp[3];
}

extern "C" void kernel_launch(void* const* d_in, const int* in_sizes, int n_in,
                              void* d_out, int out_size, void* d_ws, size_t ws_size,
                              hipStream_t stream)
{
    const float* hp     = (const float*)d_in[0];
    const float* hg     = (const float*)d_in[1];
    const float* pb     = (const float*)d_in[2];
    const float* gb     = (const float*)d_in[3];
    const int*   label  = (const int*)d_in[4];
    const int*   censor = (const int*)d_in[5];
    float*       out    = (float*)d_out;

    float* partials = (float*)d_ws;                           // ABLK*ND = 64 KiB
    float* lpart    = partials + (size_t)ABLK * ND;           // BBLK floats

    bank_partial_kernel<<<ABLK, 256, 0, stream>>>(pb, gb, partials);
    loss_kernel        <<<BBLK, 256, 0, stream>>>(hp, hg, label, censor,
                                                  partials, lpart);
    final_kernel       <<<1,    256, 0, stream>>>(lpart, out);
}